// Round 8
// baseline (417.038 us; speedup 1.0000x reference)
//
#include <hip/hip_runtime.h>
#include <hip/hip_cooperative_groups.h>

namespace cg = cooperative_groups;

// N0=N1=100000, K=16, D_MODEL=64, D_ATTN=32, H=4, dh_attn=8, dh_val=16
// r11: single cooperative fused kernel: [frag-build + cpad4] -> proj (grid-
//      stride) -> threadfence + grid.sync -> attn (grid-stride, r10 body
//      verbatim). Distinguishes inter-launch overhead (H1) from harness floor
//      (H2). Fallback to the r10 3-kernel path if coop launch is unavailable.
// Layouts: Kh[n0][32] f16 (64B rows), Vh[n0][64] f16 (128B rows = 1 line),
//          Qf[n1][32] f32, cpad4[n0] float4.

using half8   = __attribute__((ext_vector_type(8))) _Float16;
using floatx4 = __attribute__((ext_vector_type(4))) float;

template<int CTRL>
__device__ __forceinline__ float dppAdd(float x) {
    int y = __builtin_amdgcn_update_dpp(0, __float_as_int(x), CTRL, 0xF, 0xF, true);
    return x + __int_as_float(y);
}
__device__ __forceinline__ float grpSum4(float x) {
    x = dppAdd<0x124>(x);   // row_ror:4
    x = dppAdd<0x128>(x);   // row_ror:8
    return x;
}

// ===========================================================================
// Fused cooperative kernel
// ===========================================================================
__global__ __launch_bounds__(256, 4) void fused_kernel(
    const float* __restrict__ coords0, const float* __restrict__ coords1,
    const float* __restrict__ feats0, const float* __restrict__ feats1,
    const int*   __restrict__ knn,
    const float* __restrict__ Wq, const float* __restrict__ bq,
    const float* __restrict__ Wk, const float* __restrict__ bk,
    const float* __restrict__ Wv, const float* __restrict__ bv,
    _Float16* __restrict__ Kh, _Float16* __restrict__ Vh,
    float* __restrict__ Qf, floatx4* __restrict__ cpad4,
    float* __restrict__ out, float* __restrict__ outIdx,
    int n0, int n1, int tiles0, int tiles1, int ngroups)
{
    __shared__ __align__(16) char smem[28672];

    const int tid  = threadIdx.x;
    const int wave = tid >> 6;
    const int lane = tid & 63;
    const int l15  = lane & 15;
    const int quad = lane >> 4;
    const int bid  = (int)blockIdx.x;
    const int NB   = (int)gridDim.x;

    // ---------------- Phase A0: fragments into LDS + cpad4 fill -------------
    _Float16* sFragKV = (_Float16*)smem;            // 6144 halfs
    _Float16* sFragQ  = (_Float16*)(smem + 12288);  // 2048 halfs
    _Float16* sOut    = (_Float16*)(smem + 16384);  // 6144 halfs

    for (int e = tid; e < 6144; e += 256) {
        int j = e & 7, ln = (e >> 3) & 63, h = (e >> 9) & 1, t = e >> 10;
        int k = h * 32 + ((ln >> 4) * 8) + j;
        int n = t * 16 + (ln & 15);
        float v = (n < 32) ? Wk[k * 32 + n] : Wv[k * 64 + (n - 32)];
        sFragKV[e] = (_Float16)v;
    }
    for (int e = tid; e < 2048; e += 256) {
        int j = e & 7, ln = (e >> 3) & 63, h = (e >> 9) & 1, t = e >> 10;
        int k = h * 32 + ((ln >> 4) * 8) + j;
        int n = t * 16 + (ln & 15);
        sFragQ[e] = (_Float16)Wq[k * 32 + n];
    }
    for (int i = bid * 256 + tid; i < n0; i += NB * 256) {
        floatx4 c = { coords0[(size_t)i*3+0], coords0[(size_t)i*3+1],
                      coords0[(size_t)i*3+2], 0.f };
        cpad4[i] = c;
    }
    __syncthreads();

    // ---------------- Phase A1: KV tiles (grid-stride) ----------------------
    {
        const half8* bf = (const half8*)sFragKV;
        float bb[6];
        #pragma unroll
        for (int t = 0; t < 6; t++) {
            int n = t * 16 + l15;
            bb[t] = (n < 32) ? bk[n] : bv[n - 32];
        }

        for (int tile = bid; tile < tiles0; tile += NB) {
            const int rowBase = tile * 64;
            const int m0   = rowBase + wave * 16;
            const int row  = m0 + l15;
            const int rowc = (row < n0) ? row : (n0 - 1);
            const floatx4* X4 = (const floatx4*)(feats0 + (size_t)rowc * 64);
            floatx4 f0 = X4[quad * 2 + 0], f1 = X4[quad * 2 + 1];
            floatx4 f2 = X4[quad * 2 + 8], f3 = X4[quad * 2 + 9];
            half8 a0, a1;
            a0[0]=(_Float16)f0.x; a0[1]=(_Float16)f0.y; a0[2]=(_Float16)f0.z; a0[3]=(_Float16)f0.w;
            a0[4]=(_Float16)f1.x; a0[5]=(_Float16)f1.y; a0[6]=(_Float16)f1.z; a0[7]=(_Float16)f1.w;
            a1[0]=(_Float16)f2.x; a1[1]=(_Float16)f2.y; a1[2]=(_Float16)f2.z; a1[3]=(_Float16)f2.w;
            a1[4]=(_Float16)f3.x; a1[5]=(_Float16)f3.y; a1[6]=(_Float16)f3.z; a1[7]=(_Float16)f3.w;

            floatx4 acc[6];
            #pragma unroll
            for (int t = 0; t < 6; t++) acc[t] = (floatx4){bb[t], bb[t], bb[t], bb[t]};
            #pragma unroll
            for (int t = 0; t < 6; t++) {
                acc[t] = __builtin_amdgcn_mfma_f32_16x16x32_f16(a0, bf[(t*2+0)*64 + lane], acc[t], 0,0,0);
                acc[t] = __builtin_amdgcn_mfma_f32_16x16x32_f16(a1, bf[(t*2+1)*64 + lane], acc[t], 0,0,0);
            }

            // wave-private sOut slice rows [wave*16, wave*16+16), 96 halfs/row
            #pragma unroll
            for (int t = 0; t < 6; t++)
                #pragma unroll
                for (int r = 0; r < 4; r++)
                    sOut[(wave * 16 + quad * 4 + r) * 96 + t * 16 + l15] = (_Float16)acc[t][r];

            const half8* so8 = (const half8*)sOut;   // 12 chunks per row
            {   // K: 16 rows x 4 chunks = 64 chunks, one per lane
                int r = lane >> 2, ck = lane & 3;
                int gr = m0 + r;
                if (gr < n0)
                    *((half8*)(Kh + (size_t)gr * 32) + ck) = so8[(wave*16 + r) * 12 + ck];
            }
            {   // V: 16 rows x 8 chunks = 128 chunks, two per lane
                int vc = lane & 7;
                #pragma unroll
                for (int u = 0; u < 2; u++) {
                    int r = (lane >> 3) + u * 8;
                    int gr = m0 + r;
                    if (gr < n0)
                        *((half8*)(Vh + (size_t)gr * 64) + vc) = so8[(wave*16 + r) * 12 + 4 + vc];
                }
            }
        }
    }

    // ---------------- Phase A2: Q tiles (grid-stride) -----------------------
    {
        const half8* bf = (const half8*)sFragQ;
        float bb[2];
        #pragma unroll
        for (int t = 0; t < 2; t++) bb[t] = bq[t * 16 + l15];

        for (int tile = bid; tile < tiles1; tile += NB) {
            const int rowBase = tile * 64;
            const int m0   = rowBase + wave * 16;
            const int row  = m0 + l15;
            const int rowc = (row < n1) ? row : (n1 - 1);
            const floatx4* X4 = (const floatx4*)(feats1 + (size_t)rowc * 64);
            floatx4 f0 = X4[quad * 2 + 0], f1 = X4[quad * 2 + 1];
            floatx4 f2 = X4[quad * 2 + 8], f3 = X4[quad * 2 + 9];
            half8 a0, a1;
            a0[0]=(_Float16)f0.x; a0[1]=(_Float16)f0.y; a0[2]=(_Float16)f0.z; a0[3]=(_Float16)f0.w;
            a0[4]=(_Float16)f1.x; a0[5]=(_Float16)f1.y; a0[6]=(_Float16)f1.z; a0[7]=(_Float16)f1.w;
            a1[0]=(_Float16)f2.x; a1[1]=(_Float16)f2.y; a1[2]=(_Float16)f2.z; a1[3]=(_Float16)f2.w;
            a1[4]=(_Float16)f3.x; a1[5]=(_Float16)f3.y; a1[6]=(_Float16)f3.z; a1[7]=(_Float16)f3.w;

            floatx4 acc[2];
            #pragma unroll
            for (int t = 0; t < 2; t++) acc[t] = (floatx4){bb[t], bb[t], bb[t], bb[t]};
            #pragma unroll
            for (int t = 0; t < 2; t++) {
                acc[t] = __builtin_amdgcn_mfma_f32_16x16x32_f16(a0, bf[(t*2+0)*64 + lane], acc[t], 0,0,0);
                acc[t] = __builtin_amdgcn_mfma_f32_16x16x32_f16(a1, bf[(t*2+1)*64 + lane], acc[t], 0,0,0);
            }
            #pragma unroll
            for (int t = 0; t < 2; t++)
                #pragma unroll
                for (int r = 0; r < 4; r++) {
                    int ro = m0 + quad * 4 + r;
                    if (ro < n1) Qf[(size_t)ro * 32 + t * 16 + l15] = acc[t][r];
                }
        }
    }

    // ---------------- grid-wide barrier (cross-XCD visibility) --------------
    __threadfence();
    cg::this_grid().sync();
    __syncthreads();

    // ---------------- Phase B: attention (grid-stride, r10 body) ------------
    float   (*sQ)[36]      = (float(*)[36])   (smem + 0);      // 2304 B
    float   (*sWk3)[32]    = (float(*)[32])   (smem + 2304);   //  384 B
    float   (*sWv3)[64]    = (float(*)[64])   (smem + 2688);   //  768 B
    float   (*sT)[12]      = (float(*)[12])   (smem + 3456);   //  768 B
    int     (*sIdx)[16]    = (int(*)[16])     (smem + 4224);   // 1024 B
    int     (*sIdxLin)[16] = (int(*)[16])     (smem + 5248);   // 1024 B
    floatx4 (*sRel)[16]    = (floatx4(*)[16]) (smem + 6272);   // 4096 B
    floatx4 (*sRbar)[4]    = (floatx4(*)[4])  (smem + 10368);  // 1024 B
    float   (*sA)[68]      = (float(*)[68])   (smem + 11392);  // 4352 B

    for (int e = tid; e < 288; e += 256) {
        if (e < 96) ((float*)sWk3)[e] = Wk[2048 + e];
        else        ((float*)sWv3)[e - 96] = Wv[4096 + (e - 96)];
    }

    const int p = tid >> 4;
    const int j = tid & 15;
    const int g    = j & 7;
    const int hf   = j >> 3;
    const int h    = (j >> 1) & 3;
    const int slot = ((j & 1) << 3) + (j >> 1);
    const int sub  = j >> 2;
    const int c4   = j & 3;

    for (int grp = bid; grp < ngroups; grp += NB) {
        __syncthreads();   // protect prev iteration's LDS reads
        if (tid < 128) {   // stage Q rows for this group's 16 points
            int pt = tid >> 3, cq = tid & 7;
            int r = grp * 16 + pt;
            if (r >= n1) r = n1 - 1;
            ((floatx4*)&sQ[pt][0])[cq] = ((const floatx4*)Qf)[(size_t)r * 8 + cq];
        }
        __syncthreads();

        const int n = grp * 16 + p;
        const bool valid = (n < n1);
        const int nc = valid ? n : (n1 - 1);

        const int idx = knn[nc * 16 + j];

        sIdxLin[p][j]  = idx;
        sIdx[p][slot]  = idx;

        floatx4 cg4 = cpad4[idx];
        const float r0 = cg4[0] - coords1[nc * 3 + 0];
        const float r1 = cg4[1] - coords1[nc * 3 + 1];
        const float r2 = cg4[2] - coords1[nc * 3 + 2];
        sRel[p][j] = (floatx4){r0, r1, r2, 0.f};

        if (j < 12) {
            int c = j >> 2, h2 = j & 3;
            float t = 0.f;
            #pragma unroll
            for (int i = 0; i < 8; i++)
                t = fmaf(sWk3[c][h2 * 8 + i], sQ[p][h2 * 8 + i], t);
            sT[p][j] = t;
        }

        // cooperative K gather: 4 lanes cover one 64B K row
        int nbIdx[4];
        #pragma unroll
        for (int t = 0; t < 4; t++) nbIdx[t] = sIdxLin[p][t * 4 + sub];
        half8 kk[4];
        #pragma unroll
        for (int t = 0; t < 4; t++)
            kk[t] = *(const half8*)(Kh + (size_t)nbIdx[t] * 32 + c4 * 8);

        // V gather: 8-lane groups cover one 128B V row = one cache line
        const int4* si4 = (const int4*)&sIdx[p][hf * 8];
        int4 viA = si4[0], viB = si4[1];
        int vIdx[8] = {viA.x, viA.y, viA.z, viA.w, viB.x, viB.y, viB.z, viB.w};
        half8 v8[8];
        #pragma unroll
        for (int s = 0; s < 8; s++)
            v8[s] = *(const half8*)(Vh + (size_t)vIdx[s] * 64 + g * 8);

        // distributed logits: lane owns (nb = t*4+sub, head c4)
        const float scale = 0.35355339059327373f;  // 1/sqrt(8)
        floatx4 qa = ((const floatx4*)&sQ[p][0])[c4 * 2 + 0];
        floatx4 qb = ((const floatx4*)&sQ[p][0])[c4 * 2 + 1];
        const float t0 = sT[p][0 * 4 + c4];
        const float t1 = sT[p][1 * 4 + c4];
        const float t2 = sT[p][2 * 4 + c4];

        floatx4 rl[4];
        float e[4];
        #pragma unroll
        for (int t = 0; t < 4; t++) {
            rl[t] = sRel[p][t * 4 + sub];
            float acc = rl[t][0] * t0 + rl[t][1] * t1 + rl[t][2] * t2;
            acc = fmaf(qa[0], (float)kk[t][0], acc);
            acc = fmaf(qa[1], (float)kk[t][1], acc);
            acc = fmaf(qa[2], (float)kk[t][2], acc);
            acc = fmaf(qa[3], (float)kk[t][3], acc);
            acc = fmaf(qb[0], (float)kk[t][4], acc);
            acc = fmaf(qb[1], (float)kk[t][5], acc);
            acc = fmaf(qb[2], (float)kk[t][6], acc);
            acc = fmaf(qb[3], (float)kk[t][7], acc);
            e[t] = __expf(acc * scale);
        }
        float ssum = (e[0] + e[1]) + (e[2] + e[3]);
        ssum = grpSum4(ssum);
        const float rinv = __builtin_amdgcn_rcpf(ssum);

        float a_t[4];
        #pragma unroll
        for (int t = 0; t < 4; t++) a_t[t] = e[t] * rinv;

        #pragma unroll
        for (int t = 0; t < 4; t++) {
            int nb = t * 4 + sub;
            sA[p][c4 * 16 + ((nb & 1) << 3) + (nb >> 1)] = a_t[t];
        }

        {
            float pr0 = 0.f, pr1 = 0.f, pr2 = 0.f;
            #pragma unroll
            for (int t = 0; t < 4; t++) {
                pr0 = fmaf(a_t[t], rl[t][0], pr0);
                pr1 = fmaf(a_t[t], rl[t][1], pr1);
                pr2 = fmaf(a_t[t], rl[t][2], pr2);
            }
            pr0 = grpSum4(pr0);
            pr1 = grpSum4(pr1);
            pr2 = grpSum4(pr2);
            if (sub == 0) sRbar[p][c4] = (floatx4){pr0, pr1, pr2, 0.f};
        }

        if (valid) outIdx[n * 16 + j] = (float)idx;

        const floatx4* a4 = (const floatx4*)&sA[p][h * 16 + hf * 8];
        floatx4 aw0 = a4[0], aw1 = a4[1];
        float av[8] = {aw0[0], aw0[1], aw0[2], aw0[3], aw1[0], aw1[1], aw1[2], aw1[3]};

        floatx4 rb = sRbar[p][h];

        float acc8[8] = {0,0,0,0,0,0,0,0};
        #pragma unroll
        for (int s = 0; s < 8; s++)
            #pragma unroll
            for (int i = 0; i < 8; i++)
                acc8[i] = fmaf(av[s], (float)v8[s][i], acc8[i]);

        #pragma unroll
        for (int i = 0; i < 8; i++) acc8[i] = dppAdd<0x128>(acc8[i]);

        #pragma unroll
        for (int i = 0; i < 8; i++)
            acc8[i] += rb[0] * sWv3[0][8 * g + i] + rb[1] * sWv3[1][8 * g + i] + rb[2] * sWv3[2][8 * g + i];

        if (valid) {
            floatx4 st = { acc8[hf * 4 + 0], acc8[hf * 4 + 1], acc8[hf * 4 + 2], acc8[hf * 4 + 3] };
            ((floatx4*)out)[(size_t)n * 16 + g * 2 + hf] = st;
        }
    }
}

// ===========================================================================
// Fallback path: r10 three-kernel pipeline (verbatim)
// ===========================================================================
__global__ __launch_bounds__(256) void prep_weights(
    const float* __restrict__ Wq, const float* __restrict__ Wk,
    const float* __restrict__ Wv, const float* __restrict__ coords0,
    _Float16* __restrict__ fragKV, _Float16* __restrict__ fragQ,
    floatx4* __restrict__ cpad4, int n0)
{
    const int stride = gridDim.x * 256;
    const int base = blockIdx.x * 256 + threadIdx.x;
    for (int e = base; e < 6144; e += stride) {
        int j = e & 7, ln = (e >> 3) & 63, h = (e >> 9) & 1, t = e >> 10;
        int k = h * 32 + ((ln >> 4) * 8) + j;
        int n = t * 16 + (ln & 15);
        float v = (n < 32) ? Wk[k * 32 + n] : Wv[k * 64 + (n - 32)];
        fragKV[e] = (_Float16)v;
    }
    for (int e = base; e < 2048; e += stride) {
        int j = e & 7, ln = (e >> 3) & 63, h = (e >> 9) & 1, t = e >> 10;
        int k = h * 32 + ((ln >> 4) * 8) + j;
        int n = t * 16 + (ln & 15);
        fragQ[e] = (_Float16)Wq[k * 32 + n];
    }
    for (int i = base; i < n0; i += stride) {
        floatx4 c = { coords0[(size_t)i*3+0], coords0[(size_t)i*3+1],
                      coords0[(size_t)i*3+2], 0.f };
        cpad4[i] = c;
    }
}

__global__ __launch_bounds__(256, 4) void proj_fused(
    const float* __restrict__ feats0, const float* __restrict__ feats1,
    const _Float16* __restrict__ fragKV, const _Float16* __restrict__ fragQ,
    const float* __restrict__ bq, const float* __restrict__ bk,
    const float* __restrict__ bv,
    _Float16* __restrict__ Kh, _Float16* __restrict__ Vh, float* __restrict__ Qf,
    int n0, int n1, int nbKV, int nbQ, int tiles0, int tiles1)
{
    __shared__ __align__(16) _Float16 sFrag[6144];
    __shared__ __align__(16) _Float16 sOut[6144];

    const int tid  = threadIdx.x;
    const int wave = tid >> 6;
    const int lane = tid & 63;
    const int l15  = lane & 15;
    const int quad = lane >> 4;
    const int bid  = (int)blockIdx.x;

    if (bid < nbKV) {
        half8* sF8 = (half8*)sFrag;
        const half8* fk8 = (const half8*)fragKV;
        for (int c = tid; c < 768; c += 256) sF8[c] = fk8[c];
        __syncthreads();
        const half8* bf = (const half8*)sFrag;

        float bb[6];
        #pragma unroll
        for (int t = 0; t < 6; t++) {
            int n = t * 16 + l15;
            bb[t] = (n < 32) ? bk[n] : bv[n - 32];
        }

        for (int tile = bid; tile < tiles0; tile += nbKV) {
            const int rowBase = tile * 64;
            const int m0   = rowBase + wave * 16;
            const int row  = m0 + l15;
            const int rowc = (row < n0) ? row : (n0 - 1);
            const floatx4* X4 = (const floatx4*)(feats0 + (size_t)rowc * 64);
            floatx4 f0 = X4[quad * 2 + 0], f1 = X4[quad * 2 + 1];
            floatx4 f2 = X4[quad * 2 + 8], f3 = X4[quad * 2 + 9];
            half8 a0, a1;
            a0[0]=(_Float16)f0.x; a0[1]=(_Float16)f0.y; a0[2]=(_Float16)f0.z; a0[3]=(_Float16)f0.w;
            a0[4]=(_Float16)f1.x; a0[5]=(_Float16)f1.y; a0[6]=(_Float16)f1.z; a0[7]=(_Float16)f1.w;
            a1[0]=(_Float16)f2.x; a1[1]=(_Float16)f2.y; a1[2]=(_Float16)f2.z; a1[3]=(_Float16)f2.w;
            a1[4]=(_Float16)f3.x; a1[5]=(_Float16)f3.y; a1[6]=(_Float16)f3.z; a1[7]=(_Float16)f3.w;

            floatx4 acc[6];
            #pragma unroll
            for (int t = 0; t < 6; t++) acc[t] = (floatx4){bb[t], bb[t], bb[t], bb[t]};
            #pragma unroll
            for (int t = 0; t < 6; t++) {
                acc[t] = __builtin_amdgcn_mfma_f32_16x16x32_f16(a0, bf[(t*2+0)*64 + lane], acc[t], 0,0,0);
                acc[t] = __builtin_amdgcn_mfma_f32_16x16x32_f16(a1, bf[(t*2+1)*64 + lane], acc[t], 0,0,0);
            }

            #pragma unroll
            for (int t = 0; t < 6; t++)
                #pragma unroll
                for (int r = 0; r < 4; r++)
                    sOut[(wave * 16 + quad * 4 + r) * 96 + t * 16 + l15] = (_Float16)acc[t][r];

            const half8* so8 = (const half8*)sOut;
            {
                int r = lane >> 2, ck = lane & 3;
                int gr = m0 + r;
                if (gr < n0)
                    *((half8*)(Kh + (size_t)gr * 32) + ck) = so8[(wave*16 + r) * 12 + ck];
            }
            {
                int vc = lane & 7;
                #pragma unroll
                for (int u = 0; u < 2; u++) {
                    int r = (lane >> 3) + u * 8;
                    int gr = m0 + r;
                    if (gr < n0)
                        *((half8*)(Vh + (size_t)gr * 64) + vc) = so8[(wave*16 + r) * 12 + 4 + vc];
                }
            }
        }
    } else {
        half8* sF8 = (half8*)sFrag;
        const half8* fq8 = (const half8*)fragQ;
        for (int c = tid; c < 256; c += 256) sF8[c] = fq8[c];
        __syncthreads();
        const half8* bf = (const half8*)sFrag;

        float bb[2];
        #pragma unroll
        for (int t = 0; t < 2; t++) bb[t] = bq[t * 16 + l15];

        for (int tile = bid - nbKV; tile < tiles1; tile += nbQ) {
            const int rowBase = tile * 64;
            const int m0   = rowBase + wave * 16;
            const int row  = m0 + l15;
            const int rowc = (row < n1) ? row : (n1 - 1);
            const floatx4* X4 = (const floatx4*)(feats1 + (size_t)rowc * 64);
            floatx4 f0 = X4[quad * 2 + 0], f1 = X4[quad * 2 + 1];
            floatx4 f2 = X4[quad * 2 + 8], f3 = X4[quad * 2 + 9];
            half8 a0, a1;
            a0[0]=(_Float16)f0.x; a0[1]=(_Float16)f0.y; a0[2]=(_Float16)f0.z; a0[3]=(_Float16)f0.w;
            a0[4]=(_Float16)f1.x; a0[5]=(_Float16)f1.y; a0[6]=(_Float16)f1.z; a0[7]=(_Float16)f1.w;
            a1[0]=(_Float16)f2.x; a1[1]=(_Float16)f2.y; a1[2]=(_Float16)f2.z; a1[3]=(_Float16)f2.w;
            a1[4]=(_Float16)f3.x; a1[5]=(_Float16)f3.y; a1[6]=(_Float16)f3.z; a1[7]=(_Float16)f3.w;

            floatx4 acc[2];
            #pragma unroll
            for (int t = 0; t < 2; t++) acc[t] = (floatx4){bb[t], bb[t], bb[t], bb[t]};
            #pragma unroll
            for (int t = 0; t < 2; t++) {
                acc[t] = __builtin_amdgcn_mfma_f32_16x16x32_f16(a0, bf[(t*2+0)*64 + lane], acc[t], 0,0,0);
                acc[t] = __builtin_amdgcn_mfma_f32_16x16x32_f16(a1, bf[(t*2+1)*64 + lane], acc[t], 0,0,0);
            }
            #pragma unroll
            for (int t = 0; t < 2; t++)
                #pragma unroll
                for (int r = 0; r < 4; r++) {
                    int ro = m0 + quad * 4 + r;
                    if (ro < n1) Qf[(size_t)ro * 32 + t * 16 + l15] = acc[t][r];
                }
        }
    }
}

__global__ __launch_bounds__(256, 4) void attn_kernel(
    const floatx4* __restrict__ cpad4, const float* __restrict__ coords1,
    const int*   __restrict__ knn,
    const float* __restrict__ Qf,
    const _Float16* __restrict__ Kh, const _Float16* __restrict__ Vh,
    const float* __restrict__ Wk, const float* __restrict__ Wv,
    float* __restrict__ out, float* __restrict__ outIdx, int n1)
{
    __shared__ __align__(16) float sQ[16][36];
    __shared__ float sWk3[3][32];
    __shared__ float sWv3[3][64];
    __shared__ __align__(16) float sT[16][12];
    __shared__ __align__(16) int   sIdx[16][16];
    __shared__ __align__(16) int   sIdxLin[16][16];
    __shared__ __align__(16) floatx4 sRel[16][16];
    __shared__ __align__(16) floatx4 sRbar[16][4];
    __shared__ __align__(16) float sA[16][68];

    const int tid = threadIdx.x;
    for (int e = tid; e < 288; e += 256) {
        if (e < 96) ((float*)sWk3)[e] = Wk[2048 + e];
        else        ((float*)sWv3)[e - 96] = Wv[4096 + (e - 96)];
    }
    if (tid < 128) {
        int pt = tid >> 3, c4 = tid & 7;
        int r = blockIdx.x * 16 + pt;
        if (r >= n1) r = n1 - 1;
        ((floatx4*)&sQ[pt][0])[c4] = ((const floatx4*)Qf)[(size_t)r * 8 + c4];
    }
    __syncthreads();

    const int p = tid >> 4;
    const int j = tid & 15;
    const int n = blockIdx.x * 16 + p;
    const bool valid = (n < n1);
    const int nc = valid ? n : (n1 - 1);

    const int idx = knn[nc * 16 + j];

    const int g    = j & 7;
    const int hf   = j >> 3;
    const int h    = (j >> 1) & 3;
    const int slot = ((j & 1) << 3) + (j >> 1);
    const int sub  = j >> 2;
    const int c4   = j & 3;

    sIdxLin[p][j]  = idx;
    sIdx[p][slot]  = idx;

    floatx4 cg4 = cpad4[idx];
    const float r0 = cg4[0] - coords1[nc * 3 + 0];
    const float r1 = cg4[1] - coords1[nc * 3 + 1];
    const float r2 = cg4[2] - coords1[nc * 3 + 2];
    sRel[p][j] = (floatx4){r0, r1, r2, 0.f};

    if (j < 12) {
        int c = j >> 2, h2 = j & 3;
        float t = 0.f;
        #pragma unroll
        for (int i = 0; i < 8; i++)
            t = fmaf(sWk3[c][h2 * 8 + i], sQ[p][h2 * 8 + i], t);
        sT[p][j] = t;
    }

    int nbIdx[4];
    #pragma unroll
    for (int t = 0; t < 4; t++) nbIdx[t] = sIdxLin[p][t * 4 + sub];
    half8 kk[4];
    #pragma unroll
    for (int t = 0; t < 4; t++)
        kk[t] = *(const half8*)(Kh + (size_t)nbIdx[t] * 32 + c4 * 8);

    const int4* si4 = (const int4*)&sIdx[p][hf * 8];
    int4 viA = si4[0], viB = si4[1];
    int vIdx[8] = {viA.x, viA.y, viA.z, viA.w, viB.x, viB.y, viB.z, viB.w};
    half8 v8[8];
    #pragma unroll
    for (int s = 0; s < 8; s++)
        v8[s] = *(const half8*)(Vh + (size_t)vIdx[s] * 64 + g * 8);

    const float scale = 0.35355339059327373f;
    floatx4 qa = ((const floatx4*)&sQ[p][0])[c4 * 2 + 0];
    floatx4 qb = ((const floatx4*)&sQ[p][0])[c4 * 2 + 1];
    const float t0 = sT[p][0 * 4 + c4];
    const float t1 = sT[p][1 * 4 + c4];
    const float t2 = sT[p][2 * 4 + c4];

    floatx4 rl[4];
    float e[4];
    #pragma unroll
    for (int t = 0; t < 4; t++) {
        rl[t] = sRel[p][t * 4 + sub];
        float acc = rl[t][0] * t0 + rl[t][1] * t1 + rl[t][2] * t2;
        acc = fmaf(qa[0], (float)kk[t][0], acc);
        acc = fmaf(qa[1], (float)kk[t][1], acc);
        acc = fmaf(qa[2], (float)kk[t][2], acc);
        acc = fmaf(qa[3], (float)kk[t][3], acc);
        acc = fmaf(qb[0], (float)kk[t][4], acc);
        acc = fmaf(qb[1], (float)kk[t][5], acc);
        acc = fmaf(qb[2], (float)kk[t][6], acc);
        acc = fmaf(qb[3], (float)kk[t][7], acc);
        e[t] = __expf(acc * scale);
    }
    float ssum = (e[0] + e[1]) + (e[2] + e[3]);
    ssum = grpSum4(ssum);
    const float rinv = __builtin_amdgcn_rcpf(ssum);

    float a_t[4];
    #pragma unroll
    for (int t = 0; t < 4; t++) a_t[t] = e[t] * rinv;

    #pragma unroll
    for (int t = 0; t < 4; t++) {
        int nb = t * 4 + sub;
        sA[p][c4 * 16 + ((nb & 1) << 3) + (nb >> 1)] = a_t[t];
    }

    {
        float pr0 = 0.f, pr1 = 0.f, pr2 = 0.f;
        #pragma unroll
        for (int t = 0; t < 4; t++) {
            pr0 = fmaf(a_t[t], rl[t][0], pr0);
            pr1 = fmaf(a_t[t], rl[t][1], pr1);
            pr2 = fmaf(a_t[t], rl[t][2], pr2);
        }
        pr0 = grpSum4(pr0);
        pr1 = grpSum4(pr1);
        pr2 = grpSum4(pr2);
        if (sub == 0) sRbar[p][c4] = (floatx4){pr0, pr1, pr2, 0.f};
    }

    if (valid) outIdx[n * 16 + j] = (float)idx;

    const floatx4* a4 = (const floatx4*)&sA[p][h * 16 + hf * 8];
    floatx4 aw0 = a4[0], aw1 = a4[1];
    float av[8] = {aw0[0], aw0[1], aw0[2], aw0[3], aw1[0], aw1[1], aw1[2], aw1[3]};

    floatx4 rb = sRbar[p][h];

    float acc8[8] = {0,0,0,0,0,0,0,0};
    #pragma unroll
    for (int s = 0; s < 8; s++)
        #pragma unroll
        for (int i = 0; i < 8; i++)
            acc8[i] = fmaf(av[s], (float)v8[s][i], acc8[i]);

    #pragma unroll
    for (int i = 0; i < 8; i++) acc8[i] = dppAdd<0x128>(acc8[i]);

    #pragma unroll
    for (int i = 0; i < 8; i++)
        acc8[i] += rb[0] * sWv3[0][8 * g + i] + rb[1] * sWv3[1][8 * g + i] + rb[2] * sWv3[2][8 * g + i];

    if (valid) {
        floatx4 st = { acc8[hf * 4 + 0], acc8[hf * 4 + 1], acc8[hf * 4 + 2], acc8[hf * 4 + 3] };
        ((floatx4*)out)[(size_t)n * 16 + g * 2 + hf] = st;
    }
}

// ---------------------------------------------------------------------------
extern "C" void kernel_launch(void* const* d_in, const int* in_sizes, int n_in,
                              void* d_out, int out_size, void* d_ws, size_t ws_size,
                              hipStream_t stream) {
    const float* coords0 = (const float*)d_in[0];
    const float* coords1 = (const float*)d_in[1];
    const float* feats0  = (const float*)d_in[2];
    const float* feats1  = (const float*)d_in[3];
    const int*   knn     = (const int*)d_in[4];
    const float* Wq      = (const float*)d_in[5];
    const float* bq      = (const float*)d_in[6];
    const float* Wk      = (const float*)d_in[7];
    const float* bk      = (const float*)d_in[8];
    const float* Wv      = (const float*)d_in[9];
    const float* bv      = (const float*)d_in[10];

    const int n0 = in_sizes[0] / 3;
    const int n1 = in_sizes[1] / 3;

    char* ws = (char*)d_ws;
    _Float16* Kh = (_Float16*)ws;                            // [n0][32] f16, 64B rows
    _Float16* Vh = (_Float16*)(ws + (size_t)n0 * 64);        // [n0][64] f16, 128B rows
    float*    Qf = (float*)(ws + (size_t)n0 * 64 + (size_t)n0 * 128);  // [n1][32] f32
    floatx4*  cpad4 = (floatx4*)((char*)Qf + (size_t)n1 * 128);
    _Float16* fragKV = (_Float16*)(cpad4 + n0);
    _Float16* fragQ  = fragKV + 6144;

    float* out    = (float*)d_out;                           // [n1,64]
    float* outIdx = out + (size_t)n1 * 64;                   // [1,n1,16] as float

    const int tiles0 = (n0 + 63) / 64;
    const int tiles1 = (n1 + 63) / 64;
    const int ngroups = (n1 + 15) / 16;

    // ---- try the fused cooperative kernel first ----
    {
        _Float16* KhA = Kh; _Float16* VhA = Vh; float* QfA = Qf;
        floatx4* cpA = cpad4; float* outA = out; float* oiA = outIdx;
        int n0A = n0, n1A = n1, t0A = tiles0, t1A = tiles1, ngA = ngroups;
        void* kargs[] = {
            (void*)&coords0, (void*)&coords1, (void*)&feats0, (void*)&feats1,
            (void*)&knn, (void*)&Wq, (void*)&bq, (void*)&Wk, (void*)&bk,
            (void*)&Wv, (void*)&bv,
            (void*)&KhA, (void*)&VhA, (void*)&QfA, (void*)&cpA,
            (void*)&outA, (void*)&oiA,
            (void*)&n0A, (void*)&n1A, (void*)&t0A, (void*)&t1A, (void*)&ngA
        };
        hipError_t err = hipLaunchCooperativeKernel(
            (const void*)fused_kernel, dim3(1024), dim3(256), kargs, 0, stream);
        if (err == hipSuccess) return;
        (void)hipGetLastError();   // clear sticky error, fall through
    }

    // ---- fallback: r10 three-kernel pipeline ----
    const int nbKV = 512, nbQ = 256;
    prep_weights<<<128, 256, 0, stream>>>(Wq, Wk, Wv, coords0,
                                          fragKV, fragQ, cpad4, n0);
    proj_fused<<<nbKV + nbQ, 256, 0, stream>>>(feats0, feats1, fragKV, fragQ,
                                               bq, bk, bv, Kh, Vh, Qf,
                                               n0, n1, nbKV, nbQ, tiles0, tiles1);
    attn_kernel<<<ngroups, 256, 0, stream>>>(cpad4, coords1, knn,
                                             Qf, Kh, Vh, Wk, Wv, out, outIdx, n1);
}

// Round 9
// 186.297 us; speedup vs baseline: 2.2386x; 2.2386x over previous
//
#include <hip/hip_runtime.h>

// N0=N1=100000, K=16, D_MODEL=64, D_ATTN=32, H=4, dh_attn=8, dh_val=16
// r12 = r10 revert (best verified: 188.5/189.2 us). K/V split line-aligned:
//   Kh[n0][32] f16 (64B rows), Vh[n0][64] f16 (128B rows = exactly 1 L2 line),
//   Qf[n1][32] f32, cpad4[n0] float4.
// attn: coop K gather (4 lanes/row), distributed softmax (lane=(neighbor,head)),
//   DPP stride-4 reductions, LDS parity scratch for weight redistribution.
// r11's cooperative fusion REGRESSED (289 us fused vs 87 us summed): capped
// grid + grid.sync killed attn's block-level parallelism. ~122 us of the bench
// total is fixed harness overhead (proven by single-dispatch r11).

using half8   = __attribute__((ext_vector_type(8))) _Float16;
using floatx4 = __attribute__((ext_vector_type(4))) float;

template<int CTRL>
__device__ __forceinline__ float dppAdd(float x) {
    int y = __builtin_amdgcn_update_dpp(0, __float_as_int(x), CTRL, 0xF, 0xF, true);
    return x + __int_as_float(y);
}
// sum over the stride-4 group {j&3, +4, +8, +12} within a 16-lane row
__device__ __forceinline__ float grpSum4(float x) {
    x = dppAdd<0x124>(x);   // row_ror:4
    x = dppAdd<0x128>(x);   // row_ror:8
    return x;
}

// ---------------------------------------------------------------------------
// One-shot: MFMA B-fragments for [Wk|Wv] and Wq, plus coords0 -> float4 table.
// ---------------------------------------------------------------------------
__global__ __launch_bounds__(256) void prep_weights(
    const float* __restrict__ Wq, const float* __restrict__ Wk,
    const float* __restrict__ Wv, const float* __restrict__ coords0,
    _Float16* __restrict__ fragKV, _Float16* __restrict__ fragQ,
    floatx4* __restrict__ cpad4, int n0)
{
    const int stride = gridDim.x * 256;
    const int base = blockIdx.x * 256 + threadIdx.x;
    for (int e = base; e < 6144; e += stride) {
        int j = e & 7, ln = (e >> 3) & 63, h = (e >> 9) & 1, t = e >> 10;
        int k = h * 32 + ((ln >> 4) * 8) + j;
        int n = t * 16 + (ln & 15);
        float v = (n < 32) ? Wk[k * 32 + n] : Wv[k * 64 + (n - 32)];
        fragKV[e] = (_Float16)v;
    }
    for (int e = base; e < 2048; e += stride) {
        int j = e & 7, ln = (e >> 3) & 63, h = (e >> 9) & 1, t = e >> 10;
        int k = h * 32 + ((ln >> 4) * 8) + j;
        int n = t * 16 + (ln & 15);
        fragQ[e] = (_Float16)Wq[k * 32 + n];
    }
    for (int i = base; i < n0; i += stride) {
        floatx4 c = { coords0[(size_t)i*3+0], coords0[(size_t)i*3+1],
                      coords0[(size_t)i*3+2], 0.f };
        cpad4[i] = c;
    }
}

// ---------------------------------------------------------------------------
// Grid-stride fused projection. KV path writes split Kh / Vh arrays.
// ---------------------------------------------------------------------------
__global__ __launch_bounds__(256, 4) void proj_fused(
    const float* __restrict__ feats0, const float* __restrict__ feats1,
    const _Float16* __restrict__ fragKV, const _Float16* __restrict__ fragQ,
    const float* __restrict__ bq, const float* __restrict__ bk,
    const float* __restrict__ bv,
    _Float16* __restrict__ Kh, _Float16* __restrict__ Vh, float* __restrict__ Qf,
    int n0, int n1, int nbKV, int nbQ, int tiles0, int tiles1)
{
    __shared__ __align__(16) _Float16 sFrag[6144];
    __shared__ __align__(16) _Float16 sOut[6144];

    const int tid  = threadIdx.x;
    const int wave = tid >> 6;
    const int lane = tid & 63;
    const int l15  = lane & 15;
    const int quad = lane >> 4;
    const int bid  = (int)blockIdx.x;

    if (bid < nbKV) {
        half8* sF8 = (half8*)sFrag;
        const half8* fk8 = (const half8*)fragKV;
        for (int c = tid; c < 768; c += 256) sF8[c] = fk8[c];
        __syncthreads();
        const half8* bf = (const half8*)sFrag;

        float bb[6];
        #pragma unroll
        for (int t = 0; t < 6; t++) {
            int n = t * 16 + l15;
            bb[t] = (n < 32) ? bk[n] : bv[n - 32];
        }

        for (int tile = bid; tile < tiles0; tile += nbKV) {
            const int rowBase = tile * 64;
            const int m0   = rowBase + wave * 16;
            const int row  = m0 + l15;
            const int rowc = (row < n0) ? row : (n0 - 1);
            const floatx4* X4 = (const floatx4*)(feats0 + (size_t)rowc * 64);
            floatx4 f0 = X4[quad * 2 + 0], f1 = X4[quad * 2 + 1];
            floatx4 f2 = X4[quad * 2 + 8], f3 = X4[quad * 2 + 9];
            half8 a0, a1;
            a0[0]=(_Float16)f0.x; a0[1]=(_Float16)f0.y; a0[2]=(_Float16)f0.z; a0[3]=(_Float16)f0.w;
            a0[4]=(_Float16)f1.x; a0[5]=(_Float16)f1.y; a0[6]=(_Float16)f1.z; a0[7]=(_Float16)f1.w;
            a1[0]=(_Float16)f2.x; a1[1]=(_Float16)f2.y; a1[2]=(_Float16)f2.z; a1[3]=(_Float16)f2.w;
            a1[4]=(_Float16)f3.x; a1[5]=(_Float16)f3.y; a1[6]=(_Float16)f3.z; a1[7]=(_Float16)f3.w;

            floatx4 acc[6];
            #pragma unroll
            for (int t = 0; t < 6; t++) acc[t] = (floatx4){bb[t], bb[t], bb[t], bb[t]};
            #pragma unroll
            for (int t = 0; t < 6; t++) {
                acc[t] = __builtin_amdgcn_mfma_f32_16x16x32_f16(a0, bf[(t*2+0)*64 + lane], acc[t], 0,0,0);
                acc[t] = __builtin_amdgcn_mfma_f32_16x16x32_f16(a1, bf[(t*2+1)*64 + lane], acc[t], 0,0,0);
            }

            // wave-private sOut slice rows [wave*16, wave*16+16), 96 halfs/row
            #pragma unroll
            for (int t = 0; t < 6; t++)
                #pragma unroll
                for (int r = 0; r < 4; r++)
                    sOut[(wave * 16 + quad * 4 + r) * 96 + t * 16 + l15] = (_Float16)acc[t][r];

            // same wave copies its own rows out (no barrier needed)
            const half8* so8 = (const half8*)sOut;   // 12 chunks per row
            {   // K: 16 rows x 4 chunks = 64 chunks, one per lane
                int r = lane >> 2, ck = lane & 3;
                int gr = m0 + r;
                if (gr < n0)
                    *((half8*)(Kh + (size_t)gr * 32) + ck) = so8[(wave*16 + r) * 12 + ck];
            }
            {   // V: 16 rows x 8 chunks = 128 chunks, two per lane
                int vc = lane & 7;
                #pragma unroll
                for (int u = 0; u < 2; u++) {
                    int r = (lane >> 3) + u * 8;
                    int gr = m0 + r;
                    if (gr < n0)
                        *((half8*)(Vh + (size_t)gr * 64) + vc) = so8[(wave*16 + r) * 12 + 4 + vc];
                }
            }
        }
    } else {
        half8* sF8 = (half8*)sFrag;
        const half8* fq8 = (const half8*)fragQ;
        for (int c = tid; c < 256; c += 256) sF8[c] = fq8[c];
        __syncthreads();
        const half8* bf = (const half8*)sFrag;

        float bb[2];
        #pragma unroll
        for (int t = 0; t < 2; t++) bb[t] = bq[t * 16 + l15];

        for (int tile = bid - nbKV; tile < tiles1; tile += nbQ) {
            const int rowBase = tile * 64;
            const int m0   = rowBase + wave * 16;
            const int row  = m0 + l15;
            const int rowc = (row < n1) ? row : (n1 - 1);
            const floatx4* X4 = (const floatx4*)(feats1 + (size_t)rowc * 64);
            floatx4 f0 = X4[quad * 2 + 0], f1 = X4[quad * 2 + 1];
            floatx4 f2 = X4[quad * 2 + 8], f3 = X4[quad * 2 + 9];
            half8 a0, a1;
            a0[0]=(_Float16)f0.x; a0[1]=(_Float16)f0.y; a0[2]=(_Float16)f0.z; a0[3]=(_Float16)f0.w;
            a0[4]=(_Float16)f1.x; a0[5]=(_Float16)f1.y; a0[6]=(_Float16)f1.z; a0[7]=(_Float16)f1.w;
            a1[0]=(_Float16)f2.x; a1[1]=(_Float16)f2.y; a1[2]=(_Float16)f2.z; a1[3]=(_Float16)f2.w;
            a1[4]=(_Float16)f3.x; a1[5]=(_Float16)f3.y; a1[6]=(_Float16)f3.z; a1[7]=(_Float16)f3.w;

            floatx4 acc[2];
            #pragma unroll
            for (int t = 0; t < 2; t++) acc[t] = (floatx4){bb[t], bb[t], bb[t], bb[t]};
            #pragma unroll
            for (int t = 0; t < 2; t++) {
                acc[t] = __builtin_amdgcn_mfma_f32_16x16x32_f16(a0, bf[(t*2+0)*64 + lane], acc[t], 0,0,0);
                acc[t] = __builtin_amdgcn_mfma_f32_16x16x32_f16(a1, bf[(t*2+1)*64 + lane], acc[t], 0,0,0);
            }
            #pragma unroll
            for (int t = 0; t < 2; t++)
                #pragma unroll
                for (int r = 0; r < 4; r++) {
                    int ro = m0 + quad * 4 + r;
                    if (ro < n1) Qf[(size_t)ro * 32 + t * 16 + l15] = acc[t][r];
                }
        }
    }
}

// ---------------------------------------------------------------------------
// Attention. 16 lanes/point, 4 points/wave. Coop K gather from Kh, V gather
// from line-aligned Vh. Distributed softmax, DPP + LDS parity scratch.
// ---------------------------------------------------------------------------
__global__ __launch_bounds__(256, 4) void attn_kernel(
    const floatx4* __restrict__ cpad4, const float* __restrict__ coords1,
    const int*   __restrict__ knn,
    const float* __restrict__ Qf,
    const _Float16* __restrict__ Kh, const _Float16* __restrict__ Vh,
    const float* __restrict__ Wk, const float* __restrict__ Wv,
    float* __restrict__ out, float* __restrict__ outIdx, int n1)
{
    __shared__ __align__(16) float sQ[16][36];
    __shared__ float sWk3[3][32];
    __shared__ float sWv3[3][64];
    __shared__ __align__(16) float sT[16][12];     // tt[c][h2] at [p][c*4+h2]
    __shared__ __align__(16) int   sIdx[16][16];   // parity layout [p][(nb&1)*8+(nb>>1)]
    __shared__ __align__(16) int   sIdxLin[16][16];// linear [p][nb]
    __shared__ __align__(16) floatx4 sRel[16][16]; // [p][nb] = {r0,r1,r2,0}
    __shared__ __align__(16) floatx4 sRbar[16][4]; // [p][h] = {rb0,rb1,rb2,0}
    __shared__ __align__(16) float sA[16][68];     // [p][h*16 + slot(nb)] (+4 pad)

    const int tid = threadIdx.x;
    for (int e = tid; e < 288; e += 256) {
        if (e < 96) ((float*)sWk3)[e] = Wk[2048 + e];
        else        ((float*)sWv3)[e - 96] = Wv[4096 + (e - 96)];
    }
    if (tid < 128) {                      // stage Q rows for the block's 16 points
        int pt = tid >> 3, c4 = tid & 7;
        int r = blockIdx.x * 16 + pt;
        if (r >= n1) r = n1 - 1;
        ((floatx4*)&sQ[pt][0])[c4] = ((const floatx4*)Qf)[(size_t)r * 8 + c4];
    }
    __syncthreads();   // the only block barrier

    const int p = tid >> 4;          // point in block; lanes of p share a 16-lane row
    const int j = tid & 15;          // lane within point
    const int n = blockIdx.x * 16 + p;
    const bool valid = (n < n1);
    const int nc = valid ? n : (n1 - 1);

    const int idx = knn[nc * 16 + j];               // own neighbor index

    const int g    = j & 7;          // dim group for phase 2: dims [8g, 8g+8)
    const int hf   = j >> 3;         // parity of neighbors this lane accumulates
    const int h    = (j >> 1) & 3;   // head owning dims [8g, 8g+8)
    const int slot = ((j & 1) << 3) + (j >> 1);     // parity-major slot
    const int sub  = j >> 2;         // neighbor-within-quad for K-coop
    const int c4   = j & 3;          // head/chunk for K-coop

    sIdxLin[p][j]  = idx;
    sIdx[p][slot]  = idx;

    // own rel (1 float4 gather; coords1 broadcast within the 16-lane group)
    floatx4 cg = cpad4[idx];
    const float r0 = cg[0] - coords1[nc * 3 + 0];
    const float r1 = cg[1] - coords1[nc * 3 + 1];
    const float r2 = cg[2] - coords1[nc * 3 + 2];
    sRel[p][j] = (floatx4){r0, r1, r2, 0.f};

    // tt[c][h2] = q_h2 . Wk3[c, h2*8:+8]  (12 lanes compute, LDS broadcast)
    if (j < 12) {
        int c = j >> 2, h2 = j & 3;
        float t = 0.f;
        #pragma unroll
        for (int i = 0; i < 8; i++)
            t = fmaf(sWk3[c][h2 * 8 + i], sQ[p][h2 * 8 + i], t);
        sT[p][j] = t;
    }

    // ---- cooperative K gather: lane (sub,c4) loads chunk c4 (head c4's 16B)
    // of neighbors t*4+sub. 4 consecutive lanes cover one 64B K row (1 line). ----
    int nbIdx[4];
    #pragma unroll
    for (int t = 0; t < 4; t++) nbIdx[t] = sIdxLin[p][t * 4 + sub];
    half8 kk[4];
    #pragma unroll
    for (int t = 0; t < 4; t++)
        kk[t] = *(const half8*)(Kh + (size_t)nbIdx[t] * 32 + c4 * 8);

    // V gather: 8-lane groups cover one 128B V row = exactly one cache line
    const int4* si4 = (const int4*)&sIdx[p][hf * 8];
    int4 viA = si4[0], viB = si4[1];
    int vIdx[8] = {viA.x, viA.y, viA.z, viA.w, viB.x, viB.y, viB.z, viB.w};
    half8 v8[8];
    #pragma unroll
    for (int s = 0; s < 8; s++)
        v8[s] = *(const half8*)(Vh + (size_t)vIdx[s] * 64 + g * 8);

    // ---- distributed logits: lane owns (nb = t*4+sub, head c4) ----
    const float scale = 0.35355339059327373f;  // 1/sqrt(8)
    floatx4 qa = ((const floatx4*)&sQ[p][0])[c4 * 2 + 0];
    floatx4 qb = ((const floatx4*)&sQ[p][0])[c4 * 2 + 1];
    const float t0 = sT[p][0 * 4 + c4];
    const float t1 = sT[p][1 * 4 + c4];
    const float t2 = sT[p][2 * 4 + c4];

    floatx4 rl[4];
    float e[4];
    #pragma unroll
    for (int t = 0; t < 4; t++) {
        rl[t] = sRel[p][t * 4 + sub];
        float acc = rl[t][0] * t0 + rl[t][1] * t1 + rl[t][2] * t2;
        acc = fmaf(qa[0], (float)kk[t][0], acc);
        acc = fmaf(qa[1], (float)kk[t][1], acc);
        acc = fmaf(qa[2], (float)kk[t][2], acc);
        acc = fmaf(qa[3], (float)kk[t][3], acc);
        acc = fmaf(qb[0], (float)kk[t][4], acc);
        acc = fmaf(qb[1], (float)kk[t][5], acc);
        acc = fmaf(qb[2], (float)kk[t][6], acc);
        acc = fmaf(qb[3], (float)kk[t][7], acc);
        e[t] = __expf(acc * scale);     // |logit*scale| small: no max-sub
    }
    float ssum = (e[0] + e[1]) + (e[2] + e[3]);
    ssum = grpSum4(ssum);               // full denominator for head c4
    const float rinv = __builtin_amdgcn_rcpf(ssum);

    float a_t[4];
    #pragma unroll
    for (int t = 0; t < 4; t++) a_t[t] = e[t] * rinv;

    // redistribute weights: sA[p][c4*16 + slot(t*4+sub)]
    #pragma unroll
    for (int t = 0; t < 4; t++) {
        int nb = t * 4 + sub;
        sA[p][c4 * 16 + ((nb & 1) << 3) + (nb >> 1)] = a_t[t];
    }

    // rbar partials for head c4, reduced over the stride-4 lane group
    {
        float pr0 = 0.f, pr1 = 0.f, pr2 = 0.f;
        #pragma unroll
        for (int t = 0; t < 4; t++) {
            pr0 = fmaf(a_t[t], rl[t][0], pr0);
            pr1 = fmaf(a_t[t], rl[t][1], pr1);
            pr2 = fmaf(a_t[t], rl[t][2], pr2);
        }
        pr0 = grpSum4(pr0);
        pr1 = grpSum4(pr1);
        pr2 = grpSum4(pr2);
        if (sub == 0) sRbar[p][c4] = (floatx4){pr0, pr1, pr2, 0.f};
    }

    if (valid) outIdx[n * 16 + j] = (float)idx;

    // own head's weights for parity hf, contiguous over s (same-wave LDS order)
    const floatx4* a4 = (const floatx4*)&sA[p][h * 16 + hf * 8];
    floatx4 aw0 = a4[0], aw1 = a4[1];
    float av[8] = {aw0[0], aw0[1], aw0[2], aw0[3], aw1[0], aw1[1], aw1[2], aw1[3]};

    floatx4 rb = sRbar[p][h];

    // ---- phase 2: weighted V sum ----
    float acc8[8] = {0,0,0,0,0,0,0,0};
    #pragma unroll
    for (int s = 0; s < 8; s++)
        #pragma unroll
        for (int i = 0; i < 8; i++)
            acc8[i] = fmaf(av[s], (float)v8[s][i], acc8[i]);

    #pragma unroll
    for (int i = 0; i < 8; i++) acc8[i] = dppAdd<0x128>(acc8[i]);  // + other parity

    #pragma unroll
    for (int i = 0; i < 8; i++)
        acc8[i] += rb[0] * sWv3[0][8 * g + i] + rb[1] * sWv3[1][8 * g + i] + rb[2] * sWv3[2][8 * g + i];

    if (valid) {
        floatx4 st = { acc8[hf * 4 + 0], acc8[hf * 4 + 1], acc8[hf * 4 + 2], acc8[hf * 4 + 3] };
        ((floatx4*)out)[(size_t)n * 16 + g * 2 + hf] = st;
    }
}

// ---------------------------------------------------------------------------
extern "C" void kernel_launch(void* const* d_in, const int* in_sizes, int n_in,
                              void* d_out, int out_size, void* d_ws, size_t ws_size,
                              hipStream_t stream) {
    const float* coords0 = (const float*)d_in[0];
    const float* coords1 = (const float*)d_in[1];
    const float* feats0  = (const float*)d_in[2];
    const float* feats1  = (const float*)d_in[3];
    const int*   knn     = (const int*)d_in[4];
    const float* Wq      = (const float*)d_in[5];
    const float* bq      = (const float*)d_in[6];
    const float* Wk      = (const float*)d_in[7];
    const float* bk      = (const float*)d_in[8];
    const float* Wv      = (const float*)d_in[9];
    const float* bv      = (const float*)d_in[10];

    const int n0 = in_sizes[0] / 3;
    const int n1 = in_sizes[1] / 3;

    char* ws = (char*)d_ws;
    _Float16* Kh = (_Float16*)ws;                            // [n0][32] f16, 64B rows
    _Float16* Vh = (_Float16*)(ws + (size_t)n0 * 64);        // [n0][64] f16, 128B rows
    float*    Qf = (float*)(ws + (size_t)n0 * 64 + (size_t)n0 * 128);  // [n1][32] f32
    floatx4*  cpad4 = (floatx4*)((char*)Qf + (size_t)n1 * 128);
    _Float16* fragKV = (_Float16*)(cpad4 + n0);
    _Float16* fragQ  = fragKV + 6144;

    float* out    = (float*)d_out;                           // [n1,64]
    float* outIdx = out + (size_t)n1 * 64;                   // [1,n1,16] as float

    const int tiles0 = (n0 + 63) / 64;
    const int tiles1 = (n1 + 63) / 64;
    const int nbKV = 512, nbQ = 256;

    prep_weights<<<128, 256, 0, stream>>>(Wq, Wk, Wv, coords0,
                                          fragKV, fragQ, cpad4, n0);
    proj_fused<<<nbKV + nbQ, 256, 0, stream>>>(feats0, feats1, fragKV, fragQ,
                                               bq, bk, bv, Kh, Vh, Qf,
                                               n0, n1, nbKV, nbQ, tiles0, tiles1);
    attn_kernel<<<(n1 + 15) / 16, 256, 0, stream>>>(cpad4, coords1, knn,
                                                    Qf, Kh, Vh, Wk, Wv, out, outIdx, n1);
}